// Round 2
// baseline (277.205 us; speedup 1.0000x reference)
//
#include <hip/hip_runtime.h>

typedef unsigned short u16;
typedef __attribute__((ext_vector_type(8))) short bf16x8;     // MFMA A/B frag (8 bf16)
typedef __attribute__((ext_vector_type(4))) float floatx4;    // MFMA C/D frag
typedef __attribute__((ext_vector_type(8))) unsigned short u16x8; // 16B staging vector

#define NTOK 4096
#define DDIN 512
#define DDOUT 512
#define NP 8

__device__ __forceinline__ u16 f2b(float f) {
    union { float f; unsigned int u; } v; v.f = f;
    unsigned int r = (v.u + 0x7fffu + ((v.u >> 16) & 1u)) >> 16;
    return (u16)r;
}
__device__ __forceinline__ float sp(float x) {
    // softplus, overflow-safe: max(x,0) + log(1 + exp(-|x|)); fast intrinsics
    return fmaxf(x, 0.f) + __logf(1.f + __expf(-fabsf(x)));
}
__device__ __forceinline__ float sigm(float x) { return 1.f / (1.f + __expf(-x)); }

// out[i] = bf16( softplus(in[i])^2 )  -- PositiveLinearHK weight transform (fp32 in)
__global__ void prep_sqsp(const float* __restrict__ in, u16* __restrict__ out, int n) {
    int i = blockIdx.x * 256 + threadIdx.x;
    if (i < n) {
        float s = sp(in[i]);
        out[i] = f2b(s * s);
    }
}

// zwT[p][e][c] = zw[p][c][e] + zw[p][c+512][e]   (fold concat, transpose to B^T layout)
__global__ void prep_zwT(const float* __restrict__ zw, u16* __restrict__ zwT) {
    int p = blockIdx.z;
    int c0 = blockIdx.x * 32, e0 = blockIdx.y * 32;
    __shared__ float t[32][33];
    int tx = threadIdx.x, ty = threadIdx.y; // 32 x 8
    const float* base = zw + (size_t)p * 1024 * 512;
#pragma unroll
    for (int r = 0; r < 4; ++r) {
        int cl = ty * 4 + r;
        float a = base[(size_t)(c0 + cl) * 512 + e0 + tx];
        float b = base[(size_t)(c0 + cl + 512) * 512 + e0 + tx];
        t[cl][tx] = a + b;
    }
    __syncthreads();
    u16* outb = zwT + (size_t)p * 512 * 512;
#pragma unroll
    for (int r = 0; r < 4; ++r) {
        int el = ty * 4 + r;
        outb[(size_t)(e0 + el) * 512 + c0 + tx] = f2b(t[tx][el]);
    }
}

// phi[n, i*8+k] = bf16( softplus(x[n,i] + shift_k) );  xb[n,i] = bf16(x[n,i])
__global__ void phi_kernel(const float* __restrict__ x, u16* __restrict__ phi,
                           u16* __restrict__ xb) {
    int i = blockIdx.x * 256 + threadIdx.x; // over NTOK*DDIN (exact)
    float xv = x[i];
    xb[i] = f2b(xv);
    u16x8 v;
#pragma unroll
    for (int k = 0; k < 8; ++k) {
        float s = -1.f + (2.f / 7.f) * (float)k;
        v[k] = f2b(sp(xv + s));
    }
    *(u16x8*)(phi + (size_t)i * 8) = v;
}

// GEMM1: x_proj[n,o] = sum_k phi[n,k] * wphi[o,k]; epilogue -> z0[p][n][o] = sp((x_proj+phi_bias)*g1[p])
// 64x64 tile, 4 waves each 32x32 (2x2 of 16x16x32 MFMA). LDS rows padded to 40 (2-way max = free).
__launch_bounds__(256)
__global__ void gemm1(const u16* __restrict__ phi, const u16* __restrict__ wphi,
                      const float* __restrict__ phi_bias, const float* __restrict__ gate_raw,
                      u16* __restrict__ z0) {
    const int o0 = blockIdx.x * 64;
    const int n0 = blockIdx.y * 64;
    __shared__ __align__(16) u16 As[64 * 40];
    __shared__ __align__(16) u16 Bs[64 * 40];
    const int t = threadIdx.x;
    const int wave = t >> 6, lane = t & 63;
    const int wm = wave >> 1, wn = wave & 1;
    const int l15 = lane & 15, quad = lane >> 4;
    const int srow = t >> 2, sgrp = t & 3;

    floatx4 acc[2][2];
#pragma unroll
    for (int i = 0; i < 2; ++i)
#pragma unroll
        for (int j = 0; j < 2; ++j) acc[i][j] = {0.f, 0.f, 0.f, 0.f};

    for (int k0 = 0; k0 < 4096; k0 += 32) {
        u16x8 av = *(const u16x8*)(phi + (size_t)(n0 + srow) * 4096 + k0 + sgrp * 8);
        u16x8 bv = *(const u16x8*)(wphi + (size_t)(o0 + srow) * 4096 + k0 + sgrp * 8);
        __syncthreads();
        *(u16x8*)(As + srow * 40 + sgrp * 8) = av;
        *(u16x8*)(Bs + srow * 40 + sgrp * 8) = bv;
        __syncthreads();
        bf16x8 a[2], b[2];
#pragma unroll
        for (int s = 0; s < 2; ++s) {
            a[s] = *(const bf16x8*)(As + (wm * 32 + s * 16 + l15) * 40 + quad * 8);
            b[s] = *(const bf16x8*)(Bs + (wn * 32 + s * 16 + l15) * 40 + quad * 8);
        }
#pragma unroll
        for (int sm = 0; sm < 2; ++sm)
#pragma unroll
            for (int sn = 0; sn < 2; ++sn)
                acc[sm][sn] = __builtin_amdgcn_mfma_f32_16x16x32_bf16(a[sm], b[sn], acc[sm][sn], 0, 0, 0);
    }

    float g1[NP];
#pragma unroll
    for (int p = 0; p < NP; ++p) g1[p] = sigm(gate_raw[p]);

#pragma unroll
    for (int sm = 0; sm < 2; ++sm)
#pragma unroll
        for (int sn = 0; sn < 2; ++sn) {
            int gcol = o0 + wn * 32 + sn * 16 + l15;
            float pb = phi_bias[gcol];
#pragma unroll
            for (int r = 0; r < 4; ++r) {
                int grow = n0 + wm * 32 + sm * 16 + quad * 4 + r;
                float v = acc[sm][sn][r] + pb;
#pragma unroll
                for (int p = 0; p < NP; ++p) {
                    z0[(size_t)p * NTOK * DDOUT + (size_t)grow * DDOUT + gcol] = f2b(sp(v * g1[p]));
                }
            }
        }
}

// Fused GEMM2+GEMM3 + epilogue.
// acc1[n,e] = sum_d z0[p][n][d]*w2[p][e][d];  acc2[n,e] = sum_c xb[n][c]*zwT[p][e][c]
// out[n,p,e] = sp( sp((acc1+bias2)*g2) + acc2 ) + output_bias   (fp32 out)
__launch_bounds__(256)
__global__ void gemm23(const u16* __restrict__ z0, const u16* __restrict__ w2b,
                       const u16* __restrict__ xb, const u16* __restrict__ zwT,
                       const float* __restrict__ bias2, const float* __restrict__ gate_raw2,
                       const float* __restrict__ output_bias, float* __restrict__ out) {
    const int p = blockIdx.z;
    const int e0 = blockIdx.x * 64;
    const int n0 = blockIdx.y * 64;
    __shared__ __align__(16) u16 Az[64 * 40], Bw[64 * 40], Ax[64 * 40], Bz[64 * 40];
    const int t = threadIdx.x;
    const int wave = t >> 6, lane = t & 63;
    const int wm = wave >> 1, wn = wave & 1;
    const int l15 = lane & 15, quad = lane >> 4;
    const int srow = t >> 2, sgrp = t & 3;

    const u16* z0p = z0 + (size_t)p * NTOK * DDOUT;
    const u16* w2p = w2b + (size_t)p * DDOUT * DDOUT;
    const u16* zwp = zwT + (size_t)p * DDOUT * DDIN;

    floatx4 acc1[2][2], acc2[2][2];
#pragma unroll
    for (int i = 0; i < 2; ++i)
#pragma unroll
        for (int j = 0; j < 2; ++j) {
            acc1[i][j] = {0.f, 0.f, 0.f, 0.f};
            acc2[i][j] = {0.f, 0.f, 0.f, 0.f};
        }

    for (int k0 = 0; k0 < 512; k0 += 32) {
        u16x8 a1 = *(const u16x8*)(z0p + (size_t)(n0 + srow) * 512 + k0 + sgrp * 8);
        u16x8 b1 = *(const u16x8*)(w2p + (size_t)(e0 + srow) * 512 + k0 + sgrp * 8);
        u16x8 a2 = *(const u16x8*)(xb + (size_t)(n0 + srow) * 512 + k0 + sgrp * 8);
        u16x8 b2 = *(const u16x8*)(zwp + (size_t)(e0 + srow) * 512 + k0 + sgrp * 8);
        __syncthreads();
        *(u16x8*)(Az + srow * 40 + sgrp * 8) = a1;
        *(u16x8*)(Bw + srow * 40 + sgrp * 8) = b1;
        *(u16x8*)(Ax + srow * 40 + sgrp * 8) = a2;
        *(u16x8*)(Bz + srow * 40 + sgrp * 8) = b2;
        __syncthreads();
        bf16x8 az[2], bw[2], ax[2], bz[2];
#pragma unroll
        for (int s = 0; s < 2; ++s) {
            az[s] = *(const bf16x8*)(Az + (wm * 32 + s * 16 + l15) * 40 + quad * 8);
            bw[s] = *(const bf16x8*)(Bw + (wn * 32 + s * 16 + l15) * 40 + quad * 8);
            ax[s] = *(const bf16x8*)(Ax + (wm * 32 + s * 16 + l15) * 40 + quad * 8);
            bz[s] = *(const bf16x8*)(Bz + (wn * 32 + s * 16 + l15) * 40 + quad * 8);
        }
#pragma unroll
        for (int sm = 0; sm < 2; ++sm)
#pragma unroll
            for (int sn = 0; sn < 2; ++sn) {
                acc1[sm][sn] = __builtin_amdgcn_mfma_f32_16x16x32_bf16(az[sm], bw[sn], acc1[sm][sn], 0, 0, 0);
                acc2[sm][sn] = __builtin_amdgcn_mfma_f32_16x16x32_bf16(ax[sm], bz[sn], acc2[sm][sn], 0, 0, 0);
            }
    }

    const float g2p = sigm(gate_raw2[p]);

#pragma unroll
    for (int sm = 0; sm < 2; ++sm)
#pragma unroll
        for (int sn = 0; sn < 2; ++sn) {
            int gcol = e0 + wn * 32 + sn * 16 + l15;
            float bb = bias2[p * DDOUT + gcol];
            float ob = output_bias[p * DDOUT + gcol];
#pragma unroll
            for (int r = 0; r < 4; ++r) {
                int grow = n0 + wm * 32 + sm * 16 + quad * 4 + r;
                float v1 = acc1[sm][sn][r] + bb;
                float z1v = sp(v1 * g2p);
                float o = sp(z1v + acc2[sm][sn][r]) + ob;
                out[(size_t)grow * (NP * DDOUT) + p * DDOUT + gcol] = o;
            }
        }
}

extern "C" void kernel_launch(void* const* d_in, const int* in_sizes, int n_in,
                              void* d_out, int out_size, void* d_ws, size_t ws_size,
                              hipStream_t stream) {
    const float* x           = (const float*)d_in[0]; // [4096, 512]
    const float* phi_raw     = (const float*)d_in[1]; // [512, 4096]
    const float* phi_bias    = (const float*)d_in[2]; // [512]
    const float* raw_weight2 = (const float*)d_in[3]; // [8, 512, 512]
    const float* bias2       = (const float*)d_in[4]; // [8, 512]
    const float* gate_raw2   = (const float*)d_in[5]; // [8]
    const float* z_weight    = (const float*)d_in[6]; // [8, 1024, 512]
    const float* gate_raw    = (const float*)d_in[7]; // [8]
    const float* output_bias = (const float*)d_in[8]; // [8, 512]
    float* out = (float*)d_out;

    u16* ws   = (u16*)d_ws;
    u16* phi  = ws;                                  // 4096*4096 bf16
    u16* wphi = phi + (size_t)4096 * 4096;           // 512*4096
    u16* w2b  = wphi + (size_t)512 * 4096;           // 8*512*512
    u16* zwT  = w2b + (size_t)8 * 512 * 512;         // 8*512*512
    u16* z0   = zwT + (size_t)8 * 512 * 512;         // 8*4096*512
    u16* xb   = z0 + (size_t)8 * 4096 * 512;         // 4096*512
    // total: ~84 MB of workspace (bf16 staging for MFMA)

    hipLaunchKernelGGL(prep_sqsp, dim3(8192), dim3(256), 0, stream, phi_raw, wphi, 512 * 4096);
    hipLaunchKernelGGL(prep_sqsp, dim3(8192), dim3(256), 0, stream, raw_weight2, w2b, 8 * 512 * 512);
    hipLaunchKernelGGL(prep_zwT, dim3(16, 16, 8), dim3(32, 8), 0, stream, z_weight, zwT);
    hipLaunchKernelGGL(phi_kernel, dim3(8192), dim3(256), 0, stream, x, phi, xb);
    hipLaunchKernelGGL(gemm1, dim3(8, 64), dim3(256), 0, stream, phi, wphi, phi_bias, gate_raw, z0);
    hipLaunchKernelGGL(gemm23, dim3(8, 64, 8), dim3(256), 0, stream,
                       z0, w2b, xb, zwT, bias2, gate_raw2, output_bias, out);
}

// Round 3
// 224.804 us; speedup vs baseline: 1.2331x; 1.2331x over previous
//
#include <hip/hip_runtime.h>

typedef unsigned short u16;
typedef __attribute__((ext_vector_type(8))) short bf16x8;     // MFMA A/B frag (8 bf16)
typedef __attribute__((ext_vector_type(4))) float floatx4;    // MFMA C/D frag
typedef __attribute__((ext_vector_type(8))) unsigned short u16x8;
typedef __attribute__((ext_vector_type(4))) unsigned short u16x4;

#define NTOK 4096
#define DDIN 512
#define DDOUT 512
#define NP 8

__device__ __forceinline__ u16 f2b(float f) {
    union { float f; unsigned int u; } v; v.f = f;
    unsigned int r = (v.u + 0x7fffu + ((v.u >> 16) & 1u)) >> 16;
    return (u16)r;
}
__device__ __forceinline__ float sp(float x) {
    return fmaxf(x, 0.f) + __logf(1.f + __expf(-fabsf(x)));
}
__device__ __forceinline__ float sigm(float x) { return 1.f / (1.f + __expf(-x)); }

// async 16B global->LDS (wave-uniform base + lane*16 layout)
__device__ __forceinline__ void gld16(const u16* g, u16* l) {
    __builtin_amdgcn_global_load_lds((const __attribute__((address_space(1))) void*)g,
                                     (__attribute__((address_space(3))) void*)l, 16, 0, 0);
}

// out[i] = bf16( softplus(in[i])^2 )
__global__ void prep_sqsp(const float* __restrict__ in, u16* __restrict__ out, int n) {
    int i = blockIdx.x * 256 + threadIdx.x;
    if (i < n) {
        float s = sp(in[i]);
        out[i] = f2b(s * s);
    }
}

// zwT[p][e][c] = zw[p][c][e] + zw[p][c+512][e]
__global__ void prep_zwT(const float* __restrict__ zw, u16* __restrict__ zwT) {
    int p = blockIdx.z;
    int c0 = blockIdx.x * 32, e0 = blockIdx.y * 32;
    __shared__ float tb[32][33];
    int tx = threadIdx.x, ty = threadIdx.y; // 32 x 8
    const float* base = zw + (size_t)p * 1024 * 512;
#pragma unroll
    for (int r = 0; r < 4; ++r) {
        int cl = ty * 4 + r;
        float a = base[(size_t)(c0 + cl) * 512 + e0 + tx];
        float b = base[(size_t)(c0 + cl + 512) * 512 + e0 + tx];
        tb[cl][tx] = a + b;
    }
    __syncthreads();
    u16* outb = zwT + (size_t)p * 512 * 512;
#pragma unroll
    for (int r = 0; r < 4; ++r) {
        int el = ty * 4 + r;
        outb[(size_t)(e0 + el) * 512 + c0 + tx] = f2b(tb[tx][el]);
    }
}

// phi expansion + bf16 copy of x
__global__ void phi_kernel(const float* __restrict__ x, u16* __restrict__ phi,
                           u16* __restrict__ xb) {
    int i = blockIdx.x * 256 + threadIdx.x;
    float xv = x[i];
    xb[i] = f2b(xv);
    u16x8 v;
#pragma unroll
    for (int k = 0; k < 8; ++k) {
        float s = -1.f + (2.f / 7.f) * (float)k;
        v[k] = f2b(sp(xv + s));
    }
    *(u16x8*)(phi + (size_t)i * 8) = v;
}

// GEMM1 partial, split-K=4. 128x128 tile, BK=64, global_load_lds staging.
// xpart[kc][n][o] = sum_{k in chunk} phi[n,k]*wphi[o,k]   (fp32, stored in d_out scratch)
__launch_bounds__(256, 2)
__global__ void gemm1p(const u16* __restrict__ phi, const u16* __restrict__ wphi,
                       float* __restrict__ xpart) {
    __shared__ __align__(16) u16 lds[2 * 8192];
    u16* As = lds;          // [128][64]
    u16* Bs = lds + 8192;

    const int id = blockIdx.x;
    const int xcd = id & 7, local = id >> 3;
    const int kc = xcd & 3, nh = xcd >> 2;
    const int o0 = (local & 3) * 128;
    const int n0 = (nh * 16 + (local >> 2)) * 128;
    const int kbase = kc * 1024;

    const int t = threadIdx.x;
    const int wave = t >> 6, lane = t & 63;
    const int wm = wave >> 1, wn = wave & 1;
    const int l15 = lane & 15, quad = lane >> 4;
    const int srow = t >> 3, scol = (t & 7) * 8;

    floatx4 acc[4][4];
#pragma unroll
    for (int i = 0; i < 4; ++i)
#pragma unroll
        for (int j = 0; j < 4; ++j) acc[i][j] = {0.f, 0.f, 0.f, 0.f};

    for (int k0 = 0; k0 < 1024; k0 += 64) {
        const u16* ga = phi + (size_t)(n0 + srow) * 4096 + kbase + k0 + scol;
        const u16* gb = wphi + (size_t)(o0 + srow) * 4096 + kbase + k0 + scol;
        __syncthreads();
#pragma unroll
        for (int c = 0; c < 4; ++c) {
            gld16(ga + (size_t)c * 32 * 4096, As + c * 2048 + t * 8);
            gld16(gb + (size_t)c * 32 * 4096, Bs + c * 2048 + t * 8);
        }
        __syncthreads();
#pragma unroll
        for (int ks = 0; ks < 2; ++ks) {
            bf16x8 a[4], b[4];
#pragma unroll
            for (int s = 0; s < 4; ++s) {
                a[s] = *(const bf16x8*)(As + (wm * 64 + s * 16 + l15) * 64 + ks * 32 + quad * 8);
                b[s] = *(const bf16x8*)(Bs + (wn * 64 + s * 16 + l15) * 64 + ks * 32 + quad * 8);
            }
#pragma unroll
            for (int sm = 0; sm < 4; ++sm)
#pragma unroll
                for (int sn = 0; sn < 4; ++sn)
                    acc[sm][sn] = __builtin_amdgcn_mfma_f32_16x16x32_bf16(a[sm], b[sn], acc[sm][sn], 0, 0, 0);
        }
    }

    float* xp = xpart + (size_t)kc * NTOK * DDOUT;
#pragma unroll
    for (int sm = 0; sm < 4; ++sm)
#pragma unroll
        for (int sn = 0; sn < 4; ++sn) {
            int gcol = o0 + wn * 64 + sn * 16 + l15;
#pragma unroll
            for (int r = 0; r < 4; ++r) {
                int grow = n0 + wm * 64 + sm * 16 + quad * 4 + r;
                xp[(size_t)grow * DDOUT + gcol] = acc[sm][sn][r];
            }
        }
}

// reduce partials + phi_bias, expand 8 gated softplus planes -> z0 (bf16)
__global__ void reduce_ep(const float* __restrict__ xpart, const float* __restrict__ phi_bias,
                          const float* __restrict__ gate_raw, u16* __restrict__ z0) {
    int idx = blockIdx.x * 256 + threadIdx.x;      // 524288 threads, 4 floats each
    int n = idx >> 7;
    int o4 = (idx & 127) * 4;
    size_t base = (size_t)n * DDOUT + o4;
    floatx4 s = *(const floatx4*)(xpart + base);
#pragma unroll
    for (int kc = 1; kc < 4; ++kc) {
        floatx4 v = *(const floatx4*)(xpart + (size_t)kc * NTOK * DDOUT + base);
        s[0] += v[0]; s[1] += v[1]; s[2] += v[2]; s[3] += v[3];
    }
    floatx4 pb = *(const floatx4*)(phi_bias + o4);
    s[0] += pb[0]; s[1] += pb[1]; s[2] += pb[2]; s[3] += pb[3];
#pragma unroll
    for (int p = 0; p < NP; ++p) {
        float g = sigm(gate_raw[p]);
        u16x4 v;
        v[0] = f2b(sp(s[0] * g)); v[1] = f2b(sp(s[1] * g));
        v[2] = f2b(sp(s[2] * g)); v[3] = f2b(sp(s[3] * g));
        *(u16x4*)(z0 + (size_t)p * NTOK * DDOUT + base) = v;
    }
}

// Fused GEMM2+GEMM3, 128x128 tile, BK=64, global_load_lds, dual accumulators.
// XCD-pinned: p = blockIdx.x & 7 keeps each plane's z0/w2/zwT in one XCD's L2.
__launch_bounds__(256, 2)
__global__ void gemm23(const u16* __restrict__ z0, const u16* __restrict__ w2b,
                       const u16* __restrict__ xb, const u16* __restrict__ zwT,
                       const float* __restrict__ bias2, const float* __restrict__ gate_raw2,
                       const float* __restrict__ output_bias, float* __restrict__ out) {
    __shared__ __align__(16) u16 lds[4 * 8192];
    u16* A1 = lds;              // z0 tile [128][64]
    u16* B1 = lds + 8192;       // w2 tile
    u16* A2 = lds + 16384;      // xb tile
    u16* B2 = lds + 24576;      // zwT tile

    const int id = blockIdx.x;
    const int p = id & 7;
    const int local = id >> 3;
    const int e0 = (local & 3) * 128;
    const int n0 = (local >> 2) * 128;

    const int t = threadIdx.x;
    const int wave = t >> 6, lane = t & 63;
    const int wm = wave >> 1, wn = wave & 1;
    const int l15 = lane & 15, quad = lane >> 4;
    const int srow = t >> 3, scol = (t & 7) * 8;

    const u16* z0p = z0 + (size_t)p * NTOK * DDOUT;
    const u16* w2p = w2b + (size_t)p * DDOUT * DDOUT;
    const u16* zwp = zwT + (size_t)p * DDOUT * DDIN;

    floatx4 acc1[4][4], acc2[4][4];
#pragma unroll
    for (int i = 0; i < 4; ++i)
#pragma unroll
        for (int j = 0; j < 4; ++j) {
            acc1[i][j] = {0.f, 0.f, 0.f, 0.f};
            acc2[i][j] = {0.f, 0.f, 0.f, 0.f};
        }

    for (int k0 = 0; k0 < 512; k0 += 64) {
        const u16* ga1 = z0p + (size_t)(n0 + srow) * 512 + k0 + scol;
        const u16* gb1 = w2p + (size_t)(e0 + srow) * 512 + k0 + scol;
        const u16* ga2 = xb  + (size_t)(n0 + srow) * 512 + k0 + scol;
        const u16* gb2 = zwp + (size_t)(e0 + srow) * 512 + k0 + scol;
        __syncthreads();
#pragma unroll
        for (int c = 0; c < 4; ++c) {
            gld16(ga1 + (size_t)c * 32 * 512, A1 + c * 2048 + t * 8);
            gld16(gb1 + (size_t)c * 32 * 512, B1 + c * 2048 + t * 8);
            gld16(ga2 + (size_t)c * 32 * 512, A2 + c * 2048 + t * 8);
            gld16(gb2 + (size_t)c * 32 * 512, B2 + c * 2048 + t * 8);
        }
        __syncthreads();
#pragma unroll
        for (int ks = 0; ks < 2; ++ks) {
            bf16x8 a1[4], b1[4], a2[4], b2[4];
#pragma unroll
            for (int s = 0; s < 4; ++s) {
                int ro = (wm * 64 + s * 16 + l15) * 64 + ks * 32 + quad * 8;
                int co = (wn * 64 + s * 16 + l15) * 64 + ks * 32 + quad * 8;
                a1[s] = *(const bf16x8*)(A1 + ro);
                b1[s] = *(const bf16x8*)(B1 + co);
                a2[s] = *(const bf16x8*)(A2 + ro);
                b2[s] = *(const bf16x8*)(B2 + co);
            }
#pragma unroll
            for (int sm = 0; sm < 4; ++sm)
#pragma unroll
                for (int sn = 0; sn < 4; ++sn) {
                    acc1[sm][sn] = __builtin_amdgcn_mfma_f32_16x16x32_bf16(a1[sm], b1[sn], acc1[sm][sn], 0, 0, 0);
                    acc2[sm][sn] = __builtin_amdgcn_mfma_f32_16x16x32_bf16(a2[sm], b2[sn], acc2[sm][sn], 0, 0, 0);
                }
        }
    }

    const float g2p = sigm(gate_raw2[p]);
#pragma unroll
    for (int sm = 0; sm < 4; ++sm)
#pragma unroll
        for (int sn = 0; sn < 4; ++sn) {
            int gcol = e0 + wn * 64 + sn * 16 + l15;
            float bb = bias2[p * DDOUT + gcol];
            float ob = output_bias[p * DDOUT + gcol];
#pragma unroll
            for (int r = 0; r < 4; ++r) {
                int grow = n0 + wm * 64 + sm * 16 + quad * 4 + r;
                float v1 = acc1[sm][sn][r] + bb;
                float o = sp(sp(v1 * g2p) + acc2[sm][sn][r]) + ob;
                out[(size_t)grow * (NP * DDOUT) + p * DDOUT + gcol] = o;
            }
        }
}

extern "C" void kernel_launch(void* const* d_in, const int* in_sizes, int n_in,
                              void* d_out, int out_size, void* d_ws, size_t ws_size,
                              hipStream_t stream) {
    const float* x           = (const float*)d_in[0];
    const float* phi_raw     = (const float*)d_in[1];
    const float* phi_bias    = (const float*)d_in[2];
    const float* raw_weight2 = (const float*)d_in[3];
    const float* bias2       = (const float*)d_in[4];
    const float* gate_raw2   = (const float*)d_in[5];
    const float* z_weight    = (const float*)d_in[6];
    const float* gate_raw    = (const float*)d_in[7];
    const float* output_bias = (const float*)d_in[8];
    float* out = (float*)d_out;

    u16* ws   = (u16*)d_ws;
    u16* phi  = ws;                                  // 4096*4096 bf16
    u16* wphi = phi + (size_t)4096 * 4096;           // 512*4096
    u16* w2b  = wphi + (size_t)512 * 4096;           // 8*512*512
    u16* zwT  = w2b + (size_t)8 * 512 * 512;         // 8*512*512
    u16* z0   = zwT + (size_t)8 * 512 * 512;         // 8*4096*512
    u16* xb   = z0 + (size_t)8 * 4096 * 512;         // 4096*512
    // split-K partials live in d_out (33.5 MB of the 64 MB output buffer),
    // fully consumed by reduce_ep before gemm23 writes the real output.
    float* xpart = (float*)d_out;

    hipLaunchKernelGGL(prep_sqsp, dim3(8192), dim3(256), 0, stream, phi_raw, wphi, 512 * 4096);
    hipLaunchKernelGGL(prep_sqsp, dim3(8192), dim3(256), 0, stream, raw_weight2, w2b, 8 * 512 * 512);
    hipLaunchKernelGGL(prep_zwT, dim3(16, 16, 8), dim3(32, 8), 0, stream, z_weight, zwT);
    hipLaunchKernelGGL(phi_kernel, dim3(8192), dim3(256), 0, stream, x, phi, xb);
    hipLaunchKernelGGL(gemm1p, dim3(512), dim3(256), 0, stream, phi, wphi, xpart);
    hipLaunchKernelGGL(reduce_ep, dim3(2048), dim3(256), 0, stream, xpart, phi_bias, gate_raw, z0);
    hipLaunchKernelGGL(gemm23, dim3(1024), dim3(256), 0, stream,
                       z0, w2b, xb, zwT, bias2, gate_raw2, output_bias, out);
}